// Round 3
// baseline (648.058 us; speedup 1.0000x reference)
//
#include <hip/hip_runtime.h>
#include <math.h>

#define DFEAT 64
#define SCAN_B 256
#define SCAN_CHUNK 1024

static inline int imin(int a, int b) { return a < b ? a : b; }

// ---------------- preprocessing kernels ----------------

__global__ void k_zero_i32(int* __restrict__ p, int n) {
  int i = blockIdx.x * blockDim.x + threadIdx.x;
  int stride = gridDim.x * blockDim.x;
  for (; i < n; i += stride) p[i] = 0;
}

__global__ void k_degrees(const int* __restrict__ src, const int* __restrict__ dst,
                          int* __restrict__ outdeg, int* __restrict__ indeg, int E) {
  int i = blockIdx.x * blockDim.x + threadIdx.x;
  int stride = gridDim.x * blockDim.x;
  for (; i < E; i += stride) {
    atomicAdd(&outdeg[src[i]], 1);
    atomicAdd(&indeg[dst[i]], 1);
  }
}

__global__ void k_norms(const int* __restrict__ outdeg, const int* __restrict__ indeg,
                        float* __restrict__ nsrc, float* __restrict__ ndst, int n) {
  int i = blockIdx.x * blockDim.x + threadIdx.x;
  int stride = gridDim.x * blockDim.x;
  for (; i < n; i += stride) {
    int od = outdeg[i], id = indeg[i];
    nsrc[i] = od > 0 ? rsqrtf((float)od) : 0.0f;
    ndst[i] = id > 0 ? rsqrtf((float)id) : 0.0f;
  }
}

// per-chunk sums (chunk = 1024 elements, 4 per thread)
__global__ void k_chunk_sums(const int* __restrict__ in, int* __restrict__ bsums, int n) {
  __shared__ int sh[SCAN_B];
  int t = threadIdx.x;
  int base = blockIdx.x * SCAN_CHUNK + t * 4;
  int s = 0;
#pragma unroll
  for (int i = 0; i < 4; i++) {
    int idx = base + i;
    if (idx < n) s += in[idx];
  }
  sh[t] = s;
  __syncthreads();
  for (int off = SCAN_B / 2; off > 0; off >>= 1) {
    if (t < off) sh[t] += sh[t + off];
    __syncthreads();
  }
  if (t == 0) bsums[blockIdx.x] = sh[0];
}

// single-block exclusive scan of the chunk sums (nb <= 1024)
__global__ void k_scan_bsums(int* __restrict__ bsums, int nb) {
  __shared__ int sh[1024];
  int t = threadIdx.x;
  int v = (t < nb) ? bsums[t] : 0;
  sh[t] = v;
  __syncthreads();
  for (int off = 1; off < 1024; off <<= 1) {
    int x = (t >= off) ? sh[t - off] : 0;
    __syncthreads();
    sh[t] += x;
    __syncthreads();
  }
  if (t < nb) bsums[t] = sh[t] - v;  // exclusive
}

// final scan: write row offsets (exclusive) and a fill cursor copy
__global__ void k_scan_final(const int* __restrict__ in, const int* __restrict__ bsums,
                             int* __restrict__ row_off, int* __restrict__ fill_pos,
                             int n, int total) {
  __shared__ int sh[SCAN_B];
  int t = threadIdx.x;
  int base = blockIdx.x * SCAN_CHUNK + t * 4;
  int e[4];
#pragma unroll
  for (int i = 0; i < 4; i++) {
    int idx = base + i;
    e[i] = (idx < n) ? in[idx] : 0;
  }
  int tsum = e[0] + e[1] + e[2] + e[3];
  sh[t] = tsum;
  __syncthreads();
  for (int off = 1; off < SCAN_B; off <<= 1) {
    int x = (t >= off) ? sh[t - off] : 0;
    __syncthreads();
    sh[t] += x;
    __syncthreads();
  }
  int excl = sh[t] - tsum;
  int p = bsums[blockIdx.x] + excl;
#pragma unroll
  for (int i = 0; i < 4; i++) {
    int idx = base + i;
    if (idx < n) { row_off[idx] = p; fill_pos[idx] = p; }
    p += e[i];
  }
  if (blockIdx.x == 0 && t == 0) row_off[n] = total;
}

__global__ void k_fill(const int* __restrict__ src, const int* __restrict__ dst,
                       int* __restrict__ fill_pos, int* __restrict__ csr_src, int E) {
  int i = blockIdx.x * blockDim.x + threadIdx.x;
  int stride = gridDim.x * blockDim.x;
  for (; i < E; i += stride) {
    int d = dst[i];
    int p = atomicAdd(&fill_pos[d], 1);
    csr_src[p] = src[i];
  }
}

// A[i] = x[i] * nsrc[row]   (float4-vectorized; nq = N*16 quads)
__global__ void __launch_bounds__(256) k_prescale(const float* __restrict__ x,
                                                  const float* __restrict__ nsrc,
                                                  float* __restrict__ A, int nq) {
  int i = blockIdx.x * blockDim.x + threadIdx.x;
  int stride = gridDim.x * blockDim.x;
  for (; i < nq; i += stride) {
    int row = i >> 4;
    float4 v = ((const float4*)x)[i];
    float s = nsrc[row];
    v.x *= s; v.y *= s; v.z *= s; v.w *= s;
    ((float4*)A)[i] = v;
  }
}

// ---------------- fused layer kernel ----------------
// hin rows are already pre-scaled by nsrc. Per output row r (one wave):
//   s[0:64] = sum over in-edges of hin[src]         (4 edge slots x 16 feat-quads)
//   acc = relu( (s * ndst[r]) @ W + b )             (readlane-broadcast GEMM)
//   hout[r] = scale_out ? acc * nsrc[r] : acc       (fold next layer's src-norm)
// W column for this lane is register-hoisted: wreg[k] = W[k][lane], loaded once
// (64 coalesced 256B loads, L2-hot). GEMM is then pure shfl+fma, zero memory ops.
__global__ void __launch_bounds__(256) k_layer(
    const float* __restrict__ hin, const float* __restrict__ ndst,
    const float* __restrict__ nsrc, const int* __restrict__ row_off,
    const int* __restrict__ csr_src, const float* __restrict__ W,
    const float* __restrict__ b, float* __restrict__ hout, int n, int scale_out) {
  const int lane = threadIdx.x & 63;
  const int f4 = (lane & 15) * 4;  // feature offset of this lane's quad
  const int e = lane >> 4;         // edge slot 0..3

  float wreg[DFEAT];
#pragma unroll
  for (int k = 0; k < DFEAT; k++) wreg[k] = W[k * DFEAT + lane];
  const float bias = b[lane];

  int wid = blockIdx.x * (blockDim.x >> 6) + (threadIdx.x >> 6);
  int nw = gridDim.x * (blockDim.x >> 6);

  for (int r = wid; r < n; r += nw) {
    int beg = row_off[r], end = row_off[r + 1];
    float sx0 = 0, sy0 = 0, sz0 = 0, sw0 = 0;
    float sx1 = 0, sy1 = 0, sz1 = 0, sw1 = 0;
    int k = beg + e;
    // two gathers in flight per lane (edges k and k+4 of this slot)
    for (; k + 4 < end; k += 8) {
      int sA = csr_src[k];
      int sB = csr_src[k + 4];
      const float4 vA = *(const float4*)(hin + sA * DFEAT + f4);
      const float4 vB = *(const float4*)(hin + sB * DFEAT + f4);
      sx0 += vA.x; sy0 += vA.y; sz0 += vA.z; sw0 += vA.w;
      sx1 += vB.x; sy1 += vB.y; sz1 += vB.z; sw1 += vB.w;
    }
    if (k < end) {
      int sA = csr_src[k];
      const float4 vA = *(const float4*)(hin + sA * DFEAT + f4);
      sx0 += vA.x; sy0 += vA.y; sz0 += vA.z; sw0 += vA.w;
    }
    float sx = sx0 + sx1, sy = sy0 + sy1, sz = sz0 + sz1, sw = sw0 + sw1;
    // reduce across the 4 edge slots (all lanes end with quad (lane&15) sum)
    sx += __shfl_xor(sx, 16); sy += __shfl_xor(sy, 16);
    sz += __shfl_xor(sz, 16); sw += __shfl_xor(sw, 16);
    sx += __shfl_xor(sx, 32); sy += __shfl_xor(sy, 32);
    sz += __shfl_xor(sz, 32); sw += __shfl_xor(sw, 32);

    float nd = ndst[r];
    sx *= nd; sy *= nd; sz *= nd; sw *= nd;

    // GEMM: out[lane] = sum_k a[k] * W[k][lane]; a broadcast via constant-lane shfl.
    // 4 independent accumulator chains for FMA ILP. All wreg indices are literals
    // after unroll -> stays in registers.
    float a0 = bias, a1 = 0.0f, a2 = 0.0f, a3 = 0.0f;
#pragma unroll
    for (int q = 0; q < 16; q += 4) {
      a0 = fmaf(__shfl(sx, q),     wreg[4 * q + 0],  a0);
      a0 = fmaf(__shfl(sy, q),     wreg[4 * q + 1],  a0);
      a0 = fmaf(__shfl(sz, q),     wreg[4 * q + 2],  a0);
      a0 = fmaf(__shfl(sw, q),     wreg[4 * q + 3],  a0);
      a1 = fmaf(__shfl(sx, q + 1), wreg[4 * q + 4],  a1);
      a1 = fmaf(__shfl(sy, q + 1), wreg[4 * q + 5],  a1);
      a1 = fmaf(__shfl(sz, q + 1), wreg[4 * q + 6],  a1);
      a1 = fmaf(__shfl(sw, q + 1), wreg[4 * q + 7],  a1);
      a2 = fmaf(__shfl(sx, q + 2), wreg[4 * q + 8],  a2);
      a2 = fmaf(__shfl(sy, q + 2), wreg[4 * q + 9],  a2);
      a2 = fmaf(__shfl(sz, q + 2), wreg[4 * q + 10], a2);
      a2 = fmaf(__shfl(sw, q + 2), wreg[4 * q + 11], a2);
      a3 = fmaf(__shfl(sx, q + 3), wreg[4 * q + 12], a3);
      a3 = fmaf(__shfl(sy, q + 3), wreg[4 * q + 13], a3);
      a3 = fmaf(__shfl(sz, q + 3), wreg[4 * q + 14], a3);
      a3 = fmaf(__shfl(sw, q + 3), wreg[4 * q + 15], a3);
    }
    float acc = (a0 + a1) + (a2 + a3);
    acc = fmaxf(acc, 0.0f);
    if (scale_out) acc *= nsrc[r];
    hout[r * DFEAT + lane] = acc;
  }
}

// ---------------- launch ----------------

extern "C" void kernel_launch(void* const* d_in, const int* in_sizes, int n_in,
                              void* d_out, int out_size, void* d_ws, size_t ws_size,
                              hipStream_t stream) {
  const float* x = (const float*)d_in[0];
  const int* ei = (const int*)d_in[1];
  const float* Ws = (const float*)d_in[2];
  const float* bs = (const float*)d_in[3];
  float* out = (float*)d_out;

  const int N = in_sizes[0] / DFEAT;
  const int E = in_sizes[1] / 2;
  const int L = in_sizes[2] / (DFEAT * DFEAT);
  const int* src = ei;
  const int* dst = ei + E;

  // workspace carve-up (256B-aligned)
  char* w = (char*)d_ws;
  auto alloc = [&](size_t bytes) -> void* {
    void* p = (void*)w;
    w += (bytes + 255) & ~(size_t)255;
    return p;
  };
  int* outdeg = (int*)alloc(sizeof(int) * 2 * N);  // outdeg | indeg contiguous
  int* indeg = outdeg + N;
  float* nsrc = (float*)alloc(sizeof(float) * N);
  float* ndst = (float*)alloc(sizeof(float) * N);
  int* row_off = (int*)alloc(sizeof(int) * (N + 1));
  int* fill_pos = (int*)alloc(sizeof(int) * N);
  int* bsums = (int*)alloc(sizeof(int) * 1024);
  int* csr_src = (int*)alloc(sizeof(int) * E);
  float* A = (float*)alloc(sizeof(float) * N * DFEAT);
  float* B = (float*)alloc(sizeof(float) * N * DFEAT);
  (void)ws_size; (void)n_in; (void)out_size;

  const int nb = (N + SCAN_CHUNK - 1) / SCAN_CHUNK;

  k_zero_i32<<<imin((2 * N + 255) / 256, 2048), 256, 0, stream>>>(outdeg, 2 * N);
  k_degrees<<<imin((E + 255) / 256, 4096), 256, 0, stream>>>(src, dst, outdeg, indeg, E);
  k_norms<<<imin((N + 255) / 256, 2048), 256, 0, stream>>>(outdeg, indeg, nsrc, ndst, N);
  k_chunk_sums<<<nb, SCAN_B, 0, stream>>>(indeg, bsums, N);
  k_scan_bsums<<<1, 1024, 0, stream>>>(bsums, nb);
  k_scan_final<<<nb, SCAN_B, 0, stream>>>(indeg, bsums, row_off, fill_pos, N, E);
  k_fill<<<imin((E + 255) / 256, 4096), 256, 0, stream>>>(src, dst, fill_pos, csr_src, E);
  k_prescale<<<2048, 256, 0, stream>>>(x, nsrc, A, N * (DFEAT / 4));

  // layer chain: A -> B -> A -> out (gather must not alias its output)
  for (int l = 0; l < L; l++) {
    const float* hin = (l == 0) ? A : ((l & 1) ? B : A);
    float* hout = (l == L - 1) ? out : ((l & 1) ? A : B);
    k_layer<<<2048, 256, 0, stream>>>(hin, ndst, nsrc, row_off, csr_src,
                                      Ws + l * DFEAT * DFEAT, bs + l * DFEAT,
                                      hout, N, l != L - 1);
  }
}

// Round 4
// 623.401 us; speedup vs baseline: 1.0396x; 1.0396x over previous
//
#include <hip/hip_runtime.h>
#include <math.h>

#define DFEAT 64
#define SCAN_B 256
#define SCAN_CHUNK 1024
#define BUCKET_SHIFT 8   // 256 dst ids per bucket
#define NB_MAX 512       // max buckets (N<=131072)
#define SC_BLOCKS 256    // partition blocks: E/256 edges each -> long runs per bucket

static inline int imin(int a, int b) { return a < b ? a : b; }

// ---------------- preprocessing kernels ----------------

__global__ void k_zero_i32(int* __restrict__ p, int n) {
  int i = blockIdx.x * blockDim.x + threadIdx.x;
  int stride = gridDim.x * blockDim.x;
  for (; i < n; i += stride) p[i] = 0;
}

// degrees + coarse bucket histogram in one pass over the edge list
__global__ void __launch_bounds__(256) k_count(
    const int* __restrict__ src, const int* __restrict__ dst,
    int* __restrict__ outdeg, int* __restrict__ indeg,
    int* __restrict__ bucket_cnt, int E, int NB) {
  __shared__ int hist[NB_MAX];
  for (int b = threadIdx.x; b < NB; b += blockDim.x) hist[b] = 0;
  __syncthreads();
  int i = blockIdx.x * blockDim.x + threadIdx.x;
  int stride = gridDim.x * blockDim.x;
  for (; i < E; i += stride) {
    int s = src[i], d = dst[i];
    atomicAdd(&outdeg[s], 1);
    atomicAdd(&indeg[d], 1);
    atomicAdd(&hist[d >> BUCKET_SHIFT], 1);
  }
  __syncthreads();
  for (int b = threadIdx.x; b < NB; b += blockDim.x)
    if (hist[b]) atomicAdd(&bucket_cnt[b], hist[b]);
}

__global__ void k_norms(const int* __restrict__ outdeg, const int* __restrict__ indeg,
                        float* __restrict__ nsrc, float* __restrict__ ndst, int n) {
  int i = blockIdx.x * blockDim.x + threadIdx.x;
  int stride = gridDim.x * blockDim.x;
  for (; i < n; i += stride) {
    int od = outdeg[i], id = indeg[i];
    nsrc[i] = od > 0 ? rsqrtf((float)od) : 0.0f;
    ndst[i] = id > 0 ? rsqrtf((float)id) : 0.0f;
  }
}

// exclusive scan of bucket counts -> bucket write cursors (single block of 512)
__global__ void k_bucket_scan(const int* __restrict__ bucket_cnt,
                              int* __restrict__ bucket_cur, int NB) {
  __shared__ int sh[NB_MAX];
  int t = threadIdx.x;
  int v = (t < NB) ? bucket_cnt[t] : 0;
  sh[t] = v;
  __syncthreads();
  for (int off = 1; off < NB_MAX; off <<= 1) {
    int x = (t >= off) ? sh[t - off] : 0;
    __syncthreads();
    sh[t] += x;
    __syncthreads();
  }
  if (t < NB) bucket_cur[t] = sh[t] - v;  // exclusive
}

// coarse partition: scatter (dst,src) pairs grouped by bucket.
// Each block owns a contiguous edge chunk; per-bucket ranges are reserved with
// ONE global atomic per (block,bucket), so writes form long contiguous runs.
__global__ void __launch_bounds__(256) k_partition(
    const int* __restrict__ src, const int* __restrict__ dst,
    int* __restrict__ bucket_cur, int2* __restrict__ pairs, int E, int NB) {
  __shared__ int cur[NB_MAX];
  const int perBlock = (E + SC_BLOCKS - 1) / SC_BLOCKS;
  int e0 = blockIdx.x * perBlock;
  int e1 = e0 + perBlock; if (e1 > E) e1 = E;
  for (int b = threadIdx.x; b < NB; b += blockDim.x) cur[b] = 0;
  __syncthreads();
  for (int i = e0 + threadIdx.x; i < e1; i += blockDim.x)
    atomicAdd(&cur[dst[i] >> BUCKET_SHIFT], 1);
  __syncthreads();
  for (int b = threadIdx.x; b < NB; b += blockDim.x) {
    int c = cur[b];
    cur[b] = c ? atomicAdd(&bucket_cur[b], c) : 0;
  }
  __syncthreads();
  for (int i = e0 + threadIdx.x; i < e1; i += blockDim.x) {
    int d = dst[i];
    int p = atomicAdd(&cur[d >> BUCKET_SHIFT], 1);
    pairs[p] = make_int2(d, src[i]);
  }
}

// per-chunk sums (chunk = 1024 elements, 4 per thread)
__global__ void k_chunk_sums(const int* __restrict__ in, int* __restrict__ bsums, int n) {
  __shared__ int sh[SCAN_B];
  int t = threadIdx.x;
  int base = blockIdx.x * SCAN_CHUNK + t * 4;
  int s = 0;
#pragma unroll
  for (int i = 0; i < 4; i++) {
    int idx = base + i;
    if (idx < n) s += in[idx];
  }
  sh[t] = s;
  __syncthreads();
  for (int off = SCAN_B / 2; off > 0; off >>= 1) {
    if (t < off) sh[t] += sh[t + off];
    __syncthreads();
  }
  if (t == 0) bsums[blockIdx.x] = sh[0];
}

__global__ void k_scan_bsums(int* __restrict__ bsums, int nb) {
  __shared__ int sh[1024];
  int t = threadIdx.x;
  int v = (t < nb) ? bsums[t] : 0;
  sh[t] = v;
  __syncthreads();
  for (int off = 1; off < 1024; off <<= 1) {
    int x = (t >= off) ? sh[t - off] : 0;
    __syncthreads();
    sh[t] += x;
    __syncthreads();
  }
  if (t < nb) bsums[t] = sh[t] - v;  // exclusive
}

__global__ void k_scan_final(const int* __restrict__ in, const int* __restrict__ bsums,
                             int* __restrict__ row_off, int* __restrict__ fill_pos,
                             int n, int total) {
  __shared__ int sh[SCAN_B];
  int t = threadIdx.x;
  int base = blockIdx.x * SCAN_CHUNK + t * 4;
  int e[4];
#pragma unroll
  for (int i = 0; i < 4; i++) {
    int idx = base + i;
    e[i] = (idx < n) ? in[idx] : 0;
  }
  int tsum = e[0] + e[1] + e[2] + e[3];
  sh[t] = tsum;
  __syncthreads();
  for (int off = 1; off < SCAN_B; off <<= 1) {
    int x = (t >= off) ? sh[t - off] : 0;
    __syncthreads();
    sh[t] += x;
    __syncthreads();
  }
  int excl = sh[t] - tsum;
  int p = bsums[blockIdx.x] + excl;
#pragma unroll
  for (int i = 0; i < 4; i++) {
    int idx = base + i;
    if (idx < n) { row_off[idx] = p; fill_pos[idx] = p; }
    p += e[i];
  }
  if (blockIdx.x == 0 && t == 0) row_off[n] = total;
}

// fine fill from bucket-grouped pairs: each block's writes/atomics stay in a
// ~16KB L2-hot csr window -> near-1x write amplification.
__global__ void k_fill_binned(const int2* __restrict__ pairs, int* __restrict__ fill_pos,
                              int* __restrict__ csr_src, int E) {
  int i = blockIdx.x * blockDim.x + threadIdx.x;
  int stride = gridDim.x * blockDim.x;
  for (; i < E; i += stride) {
    int2 pr = pairs[i];
    int p = atomicAdd(&fill_pos[pr.x], 1);
    csr_src[p] = pr.y;
  }
}

// A[i] = x[i] * nsrc[row]   (float4-vectorized; nq = N*16 quads)
__global__ void __launch_bounds__(256) k_prescale(const float* __restrict__ x,
                                                  const float* __restrict__ nsrc,
                                                  float* __restrict__ A, int nq) {
  int i = blockIdx.x * blockDim.x + threadIdx.x;
  int stride = gridDim.x * blockDim.x;
  for (; i < nq; i += stride) {
    int row = i >> 4;
    float4 v = ((const float4*)x)[i];
    float s = nsrc[row];
    v.x *= s; v.y *= s; v.z *= s; v.w *= s;
    ((float4*)A)[i] = v;
  }
}

// ---------------- fused layer kernel ----------------
// hin rows pre-scaled by nsrc. Per output row r (one wave):
//   s[0:64] = sum over in-edges of hin[src]   (4 edge slots x 16 feat-quads,
//                                              4 float4 gathers in flight/lane)
//   acc = relu( (s * ndst[r]) @ W + b )       (readlane-broadcast GEMM, W in regs)
//   hout[r] = scale_out ? acc * nsrc[r] : acc (fold next layer's src-norm)
__global__ void __launch_bounds__(256, 4) k_layer(
    const float* __restrict__ hin, const float* __restrict__ ndst,
    const float* __restrict__ nsrc, const int* __restrict__ row_off,
    const int* __restrict__ csr_src, const float* __restrict__ W,
    const float* __restrict__ b, float* __restrict__ hout, int n, int scale_out) {
  const int lane = threadIdx.x & 63;
  const int f4 = (lane & 15) * 4;  // feature offset of this lane's quad
  const int e = lane >> 4;         // edge slot 0..3

  float wreg[DFEAT];
#pragma unroll
  for (int k = 0; k < DFEAT; k++) wreg[k] = W[k * DFEAT + lane];
  const float bias = b[lane];

  int wid = blockIdx.x * (blockDim.x >> 6) + (threadIdx.x >> 6);
  int nw = gridDim.x * (blockDim.x >> 6);

  for (int r = wid; r < n; r += nw) {
    int beg = row_off[r], end = row_off[r + 1];
    float sx0 = 0, sy0 = 0, sz0 = 0, sw0 = 0;
    float sx1 = 0, sy1 = 0, sz1 = 0, sw1 = 0;
    float sx2 = 0, sy2 = 0, sz2 = 0, sw2 = 0;
    float sx3 = 0, sy3 = 0, sz3 = 0, sw3 = 0;
    int k = beg + e;
    // 4 gathers in flight per lane: one iteration covers a deg-16 row
    for (; k + 12 < end; k += 16) {
      int sA = csr_src[k];
      int sB = csr_src[k + 4];
      int sC = csr_src[k + 8];
      int sD = csr_src[k + 12];
      const float4 vA = *(const float4*)(hin + sA * DFEAT + f4);
      const float4 vB = *(const float4*)(hin + sB * DFEAT + f4);
      const float4 vC = *(const float4*)(hin + sC * DFEAT + f4);
      const float4 vD = *(const float4*)(hin + sD * DFEAT + f4);
      sx0 += vA.x; sy0 += vA.y; sz0 += vA.z; sw0 += vA.w;
      sx1 += vB.x; sy1 += vB.y; sz1 += vB.z; sw1 += vB.w;
      sx2 += vC.x; sy2 += vC.y; sz2 += vC.z; sw2 += vC.w;
      sx3 += vD.x; sy3 += vD.y; sz3 += vD.z; sw3 += vD.w;
    }
    for (; k < end; k += 4) {
      int sA = csr_src[k];
      const float4 vA = *(const float4*)(hin + sA * DFEAT + f4);
      sx0 += vA.x; sy0 += vA.y; sz0 += vA.z; sw0 += vA.w;
    }
    float sx = (sx0 + sx1) + (sx2 + sx3);
    float sy = (sy0 + sy1) + (sy2 + sy3);
    float sz = (sz0 + sz1) + (sz2 + sz3);
    float sw = (sw0 + sw1) + (sw2 + sw3);
    // reduce across the 4 edge slots (all lanes end with quad (lane&15) sum)
    sx += __shfl_xor(sx, 16); sy += __shfl_xor(sy, 16);
    sz += __shfl_xor(sz, 16); sw += __shfl_xor(sw, 16);
    sx += __shfl_xor(sx, 32); sy += __shfl_xor(sy, 32);
    sz += __shfl_xor(sz, 32); sw += __shfl_xor(sw, 32);

    float nd = ndst[r];
    sx *= nd; sy *= nd; sz *= nd; sw *= nd;

    // GEMM: out[lane] = sum_k a[k] * W[k][lane]; broadcast via constant-lane shfl.
    float a0 = bias, a1 = 0.0f, a2 = 0.0f, a3 = 0.0f;
#pragma unroll
    for (int q = 0; q < 16; q += 4) {
      a0 = fmaf(__shfl(sx, q),     wreg[4 * q + 0],  a0);
      a0 = fmaf(__shfl(sy, q),     wreg[4 * q + 1],  a0);
      a0 = fmaf(__shfl(sz, q),     wreg[4 * q + 2],  a0);
      a0 = fmaf(__shfl(sw, q),     wreg[4 * q + 3],  a0);
      a1 = fmaf(__shfl(sx, q + 1), wreg[4 * q + 4],  a1);
      a1 = fmaf(__shfl(sy, q + 1), wreg[4 * q + 5],  a1);
      a1 = fmaf(__shfl(sz, q + 1), wreg[4 * q + 6],  a1);
      a1 = fmaf(__shfl(sw, q + 1), wreg[4 * q + 7],  a1);
      a2 = fmaf(__shfl(sx, q + 2), wreg[4 * q + 8],  a2);
      a2 = fmaf(__shfl(sy, q + 2), wreg[4 * q + 9],  a2);
      a2 = fmaf(__shfl(sz, q + 2), wreg[4 * q + 10], a2);
      a2 = fmaf(__shfl(sw, q + 2), wreg[4 * q + 11], a2);
      a3 = fmaf(__shfl(sx, q + 3), wreg[4 * q + 12], a3);
      a3 = fmaf(__shfl(sy, q + 3), wreg[4 * q + 13], a3);
      a3 = fmaf(__shfl(sz, q + 3), wreg[4 * q + 14], a3);
      a3 = fmaf(__shfl(sw, q + 3), wreg[4 * q + 15], a3);
    }
    float acc = (a0 + a1) + (a2 + a3);
    acc = fmaxf(acc, 0.0f);
    if (scale_out) acc *= nsrc[r];
    hout[r * DFEAT + lane] = acc;
  }
}

// ---------------- launch ----------------

extern "C" void kernel_launch(void* const* d_in, const int* in_sizes, int n_in,
                              void* d_out, int out_size, void* d_ws, size_t ws_size,
                              hipStream_t stream) {
  const float* x = (const float*)d_in[0];
  const int* ei = (const int*)d_in[1];
  const float* Ws = (const float*)d_in[2];
  const float* bs = (const float*)d_in[3];
  float* out = (float*)d_out;

  const int N = in_sizes[0] / DFEAT;
  const int E = in_sizes[1] / 2;
  const int L = in_sizes[2] / (DFEAT * DFEAT);
  const int* src = ei;
  const int* dst = ei + E;
  const int NB = (N + (1 << BUCKET_SHIFT) - 1) >> BUCKET_SHIFT;  // 391 for N=100K

  // workspace carve-up (256B-aligned)
  char* w = (char*)d_ws;
  auto alloc = [&](size_t bytes) -> void* {
    void* p = (void*)w;
    w += (bytes + 255) & ~(size_t)255;
    return p;
  };
  int* outdeg = (int*)alloc(sizeof(int) * (2 * N + NB_MAX));  // outdeg|indeg|bucket_cnt
  int* indeg = outdeg + N;
  int* bucket_cnt = outdeg + 2 * N;
  int* bucket_cur = (int*)alloc(sizeof(int) * NB_MAX);
  float* nsrc = (float*)alloc(sizeof(float) * N);
  float* ndst = (float*)alloc(sizeof(float) * N);
  int* row_off = (int*)alloc(sizeof(int) * (N + 1));
  int* fill_pos = (int*)alloc(sizeof(int) * N);
  int* bsums = (int*)alloc(sizeof(int) * 1024);
  int* csr_src = (int*)alloc(sizeof(int) * E);
  float* A = (float*)alloc(sizeof(float) * N * DFEAT);
  float* B = (float*)alloc(sizeof(float) * N * DFEAT);
  int2* pairs = (int2*)B;  // alias: pairs dead before layer0 writes B
  (void)ws_size; (void)n_in; (void)out_size;

  const int nb = (N + SCAN_CHUNK - 1) / SCAN_CHUNK;

  k_zero_i32<<<imin((2 * N + NB_MAX + 255) / 256, 2048), 256, 0, stream>>>(outdeg, 2 * N + NB_MAX);
  k_count<<<512, 256, 0, stream>>>(src, dst, outdeg, indeg, bucket_cnt, E, NB);
  k_norms<<<imin((N + 255) / 256, 2048), 256, 0, stream>>>(outdeg, indeg, nsrc, ndst, N);
  k_bucket_scan<<<1, NB_MAX, 0, stream>>>(bucket_cnt, bucket_cur, NB);
  k_chunk_sums<<<nb, SCAN_B, 0, stream>>>(indeg, bsums, N);
  k_scan_bsums<<<1, 1024, 0, stream>>>(bsums, nb);
  k_scan_final<<<nb, SCAN_B, 0, stream>>>(indeg, bsums, row_off, fill_pos, N, E);
  k_partition<<<SC_BLOCKS, 256, 0, stream>>>(src, dst, bucket_cur, pairs, E, NB);
  k_fill_binned<<<2048, 256, 0, stream>>>(pairs, fill_pos, csr_src, E);
  k_prescale<<<2048, 256, 0, stream>>>(x, nsrc, A, N * (DFEAT / 4));

  // layer chain: A -> B -> A -> out (gather must not alias its output)
  for (int l = 0; l < L; l++) {
    const float* hin = (l == 0) ? A : ((l & 1) ? B : A);
    float* hout = (l == L - 1) ? out : ((l & 1) ? A : B);
    k_layer<<<2048, 256, 0, stream>>>(hin, ndst, nsrc, row_off, csr_src,
                                      Ws + l * DFEAT * DFEAT, bs + l * DFEAT,
                                      hout, N, l != L - 1);
  }
}